// Round 9
// baseline (521.535 us; speedup 1.0000x reference)
//
#include <hip/hip_runtime.h>

// GraphSAGE forward, 3 layers. R9: single persistent kernel with software
// grid barriers (cooperative launch failed under graph capture in R8).
// prep (xq fp8 + Wt transposes + idxs) -> bar -> L1 -> bar -> L2 -> bar -> L3.
// Gather path fp8, self/GEMM bf16, accum f32 (R5-R7 proven numerics).
// Residency proof (deadlock-free barrier): LDS 38912 B/block -> 4 blocks/CU;
// __launch_bounds__(256,4) -> VGPR<=128 -> 4 waves/SIMD. 256CU*4=1024 >= 782.

#define KNBR 16
#define MT   64
#define LDA  272
#define NT   782     // tiles = ceil(50000/64)

typedef __attribute__((ext_vector_type(8))) short short8;
typedef __attribute__((ext_vector_type(4))) float f32x4;
typedef __attribute__((ext_vector_type(2))) float f32x2;

__device__ inline unsigned short f2bf(float f) {
    union { float f; unsigned int i; } c; c.f = f;
    unsigned int u = c.i;
    u += 0x7FFFu + ((u >> 16) & 1u);   // RNE
    return (unsigned short)(u >> 16);
}
__device__ inline unsigned char f2fp8(float v) {
    return (unsigned char)(__builtin_amdgcn_cvt_pk_fp8_f32(v, v, 0, false) & 0xFF);
}

// one-shot grid barrier, slot in [0,3). bar zeroed by hipMemsetAsync pre-launch.
__device__ __forceinline__ void grid_barrier(unsigned int* bar, int nblocks, int slot) {
    __syncthreads();
    if (threadIdx.x == 0) {
        unsigned int* cnt  = bar + slot * 32;        // 128B apart
        unsigned int* flag = cnt + 16;
        __threadfence();                             // release prior writes (device scope)
        const unsigned int v = atomicAdd(cnt, 1u);   // device-scope by default
        if (v == (unsigned int)(nblocks - 1)) {
            __hip_atomic_store(flag, 1u, __ATOMIC_RELEASE, __HIP_MEMORY_SCOPE_AGENT);
        } else {
            while (__hip_atomic_load(flag, __ATOMIC_ACQUIRE, __HIP_MEMORY_SCOPE_AGENT) == 0u)
                __builtin_amdgcn_s_sleep(2);
        }
        __threadfence();
    }
    __syncthreads();
}

// ---------------- per-layer device body (R7-proven) ----------------

template<int FO, bool RELU, bool OUTF32, bool WRITEQ, bool INF32>
__device__ __forceinline__
void layer_body(const void* __restrict__ hself,
                const unsigned char* __restrict__ hq,
                const unsigned short* __restrict__ Wt,
                void* __restrict__ outp,
                unsigned char* __restrict__ outq,
                int N, int tid, int base,
                unsigned short (*A)[LDA], const int (*idxs)[KNBR])
{
    // ---- phase 1: fp8 gather, node-pair MLP; self row -> bf16 LDS ----
    {
        const int lane16 = tid & 15;
        const int grp    = tid >> 4;
        const int f0     = lane16 * 8;
        #pragma unroll
        for (int i = 0; i < 2; ++i) {
            const int lnA = grp * 4 + i * 2;
            const int lnB = lnA + 1;
            int nA = base + lnA; if (nA >= N) nA = N - 1;
            int nB = base + lnB; if (nB >= N) nB = N - 1;

            if (INF32) {
                const float* xf = (const float*)hself;
                const float4 a0 = *reinterpret_cast<const float4*>(&xf[(size_t)nA * 128 + f0]);
                const float4 a1 = *reinterpret_cast<const float4*>(&xf[(size_t)nA * 128 + f0 + 4]);
                const float4 b0 = *reinterpret_cast<const float4*>(&xf[(size_t)nB * 128 + f0]);
                const float4 b1 = *reinterpret_cast<const float4*>(&xf[(size_t)nB * 128 + f0 + 4]);
                uint4 oa, ob;
                oa.x = (unsigned int)f2bf(a0.x) | ((unsigned int)f2bf(a0.y) << 16);
                oa.y = (unsigned int)f2bf(a0.z) | ((unsigned int)f2bf(a0.w) << 16);
                oa.z = (unsigned int)f2bf(a1.x) | ((unsigned int)f2bf(a1.y) << 16);
                oa.w = (unsigned int)f2bf(a1.z) | ((unsigned int)f2bf(a1.w) << 16);
                ob.x = (unsigned int)f2bf(b0.x) | ((unsigned int)f2bf(b0.y) << 16);
                ob.y = (unsigned int)f2bf(b0.z) | ((unsigned int)f2bf(b0.w) << 16);
                ob.z = (unsigned int)f2bf(b1.x) | ((unsigned int)f2bf(b1.y) << 16);
                ob.w = (unsigned int)f2bf(b1.z) | ((unsigned int)f2bf(b1.w) << 16);
                *reinterpret_cast<uint4*>(&A[lnA][f0]) = oa;
                *reinterpret_cast<uint4*>(&A[lnB][f0]) = ob;
            } else {
                const unsigned short* hb = (const unsigned short*)hself;
                *reinterpret_cast<uint4*>(&A[lnA][f0]) =
                    *reinterpret_cast<const uint4*>(&hb[(size_t)nA * 128 + f0]);
                *reinterpret_cast<uint4*>(&A[lnB][f0]) =
                    *reinterpret_cast<const uint4*>(&hb[(size_t)nB * 128 + f0]);
            }

            uint2 va[KNBR], vb[KNBR];
            #pragma unroll
            for (int k = 0; k < KNBR; ++k)
                va[k] = *reinterpret_cast<const uint2*>(&hq[(size_t)idxs[lnA][k] * 128 + f0]);
            #pragma unroll
            for (int k = 0; k < KNBR; ++k)
                vb[k] = *reinterpret_cast<const uint2*>(&hq[(size_t)idxs[lnB][k] * 128 + f0]);

            f32x2 a01 = {0.f,0.f}, a23 = {0.f,0.f}, a45 = {0.f,0.f}, a67 = {0.f,0.f};
            #pragma unroll
            for (int k = 0; k < KNBR; ++k) {
                a01 += __builtin_amdgcn_cvt_pk_f32_fp8(va[k].x, false);
                a23 += __builtin_amdgcn_cvt_pk_f32_fp8(va[k].x, true);
                a45 += __builtin_amdgcn_cvt_pk_f32_fp8(va[k].y, false);
                a67 += __builtin_amdgcn_cvt_pk_f32_fp8(va[k].y, true);
            }
            uint4 pA;
            pA.x = (unsigned int)f2bf(a01.x * 0.0625f) | ((unsigned int)f2bf(a01.y * 0.0625f) << 16);
            pA.y = (unsigned int)f2bf(a23.x * 0.0625f) | ((unsigned int)f2bf(a23.y * 0.0625f) << 16);
            pA.z = (unsigned int)f2bf(a45.x * 0.0625f) | ((unsigned int)f2bf(a45.y * 0.0625f) << 16);
            pA.w = (unsigned int)f2bf(a67.x * 0.0625f) | ((unsigned int)f2bf(a67.y * 0.0625f) << 16);
            *reinterpret_cast<uint4*>(&A[lnA][128 + f0]) = pA;

            f32x2 b01 = {0.f,0.f}, b23 = {0.f,0.f}, b45 = {0.f,0.f}, b67 = {0.f,0.f};
            #pragma unroll
            for (int k = 0; k < KNBR; ++k) {
                b01 += __builtin_amdgcn_cvt_pk_f32_fp8(vb[k].x, false);
                b23 += __builtin_amdgcn_cvt_pk_f32_fp8(vb[k].x, true);
                b45 += __builtin_amdgcn_cvt_pk_f32_fp8(vb[k].y, false);
                b67 += __builtin_amdgcn_cvt_pk_f32_fp8(vb[k].y, true);
            }
            uint4 pB;
            pB.x = (unsigned int)f2bf(b01.x * 0.0625f) | ((unsigned int)f2bf(b01.y * 0.0625f) << 16);
            pB.y = (unsigned int)f2bf(b23.x * 0.0625f) | ((unsigned int)f2bf(b23.y * 0.0625f) << 16);
            pB.z = (unsigned int)f2bf(b45.x * 0.0625f) | ((unsigned int)f2bf(b45.y * 0.0625f) << 16);
            pB.w = (unsigned int)f2bf(b67.x * 0.0625f) | ((unsigned int)f2bf(b67.y * 0.0625f) << 16);
            *reinterpret_cast<uint4*>(&A[lnB][128 + f0]) = pB;
        }
    }
    __syncthreads();

    // ---- phase 2: [64 x 256] @ [256 x FO] via mfma_f32_16x16x32_bf16 ----
    {
        constexpr int NCT = FO / 64;
        const int wv  = tid >> 6;
        const int l   = tid & 63;
        const int l15 = l & 15;
        const int kg  = l >> 4;

        f32x4 acc[4][NCT];
        #pragma unroll
        for (int rt = 0; rt < 4; ++rt)
            #pragma unroll
            for (int c = 0; c < NCT; ++c)
                acc[rt][c] = (f32x4){0.f, 0.f, 0.f, 0.f};

        const unsigned short* wbase[NCT];
        #pragma unroll
        for (int c = 0; c < NCT; ++c) {
            const int col = (wv * NCT + c) * 16 + l15;
            wbase[c] = Wt + (size_t)col * 256 + kg * 8;
        }

        #pragma unroll
        for (int ks = 0; ks < 8; ++ks) {
            short8 b[NCT];
            #pragma unroll
            for (int c = 0; c < NCT; ++c)
                b[c] = *reinterpret_cast<const short8*>(wbase[c] + ks * 32);
            #pragma unroll
            for (int rt = 0; rt < 4; ++rt) {
                const short8 a = *reinterpret_cast<const short8*>(&A[rt * 16 + l15][ks * 32 + kg * 8]);
                #pragma unroll
                for (int c = 0; c < NCT; ++c)
                    acc[rt][c] = __builtin_amdgcn_mfma_f32_16x16x32_bf16(a, b[c], acc[rt][c], 0, 0, 0);
            }
        }

        #pragma unroll
        for (int rt = 0; rt < 4; ++rt) {
            #pragma unroll
            for (int c = 0; c < NCT; ++c) {
                const int col = (wv * NCT + c) * 16 + l15;
                #pragma unroll
                for (int r = 0; r < 4; ++r) {
                    const int row = rt * 16 + kg * 4 + r;
                    const int n   = base + row;
                    if (n < N) {
                        float v = acc[rt][c][r];
                        if (RELU) v = fmaxf(v, 0.f);
                        if (OUTF32)
                            reinterpret_cast<float*>(outp)[(size_t)n * FO + col] = v;
                        else
                            reinterpret_cast<unsigned short*>(outp)[(size_t)n * FO + col] = f2bf(v);
                        if (WRITEQ)
                            outq[(size_t)n * FO + col] = f2fp8(v);
                    }
                }
            }
        }
    }
}

// ---------------- the single persistent kernel ----------------

__global__ __launch_bounds__(256, 4)
void fused_sage(const float* __restrict__ x, const int* __restrict__ adj,
                const float* __restrict__ W0, const float* __restrict__ W1,
                const float* __restrict__ W2,
                unsigned char* __restrict__ xq,
                unsigned short* __restrict__ h1, unsigned char* __restrict__ h1q,
                unsigned short* __restrict__ h2, unsigned char* __restrict__ h2q,
                unsigned short* __restrict__ Wt0, unsigned short* __restrict__ Wt1,
                unsigned short* __restrict__ Wt2,
                unsigned int* __restrict__ bar,
                float* __restrict__ logits, int N)
{
    __shared__ unsigned short A[MT][LDA];
    __shared__ int idxs[MT][KNBR];

    const int tid     = threadIdx.x;
    const int base    = blockIdx.x * MT;
    const int gid     = blockIdx.x * 256 + tid;
    const int gstride = gridDim.x * 256;
    const int nb      = gridDim.x;

    // ---- prep A: x -> fp8 xq (grid-stride) ----
    {
        const int total4 = N * 128 / 4;
        for (int i = gid; i < total4; i += gstride) {
            const float4 v = reinterpret_cast<const float4*>(x)[i];
            unsigned int q;
            q = __builtin_amdgcn_cvt_pk_fp8_f32(v.x, v.y, 0, false);
            q = __builtin_amdgcn_cvt_pk_fp8_f32(v.z, v.w, q, true);
            reinterpret_cast<unsigned int*>(xq)[i] = q;
        }
    }
    // ---- prep B: W transposes -> bf16 ----
    for (int id = gid; id < 81920; id += gstride) {
        const float* W; unsigned short* Wt; int FO; int loc;
        if (id < 32768)      { W = W0; Wt = Wt0; FO = 128; loc = id; }
        else if (id < 65536) { W = W1; Wt = Wt1; FO = 128; loc = id - 32768; }
        else                 { W = W2; Wt = Wt2; FO = 64;  loc = id - 65536; }
        const int j = loc >> 8;
        const int k = loc & 255;
        Wt[loc] = f2bf(W[k * FO + j]);
    }
    // ---- prep C: neighbor indices (layer-invariant) -> LDS ----
    {
        const int nn = tid & 63;
        const int q  = tid >> 6;
        int n = base + nn; if (n >= N) n = N - 1;
        #pragma unroll
        for (int rep = 0; rep < 4; ++rep) {
            const int kk = rep * 4 + q;
            idxs[nn][kk] = adj[(size_t)kk * N + n];
        }
    }

    grid_barrier(bar, nb, 0);
    layer_body<128, true,  false, true,  true >(x,  xq,  Wt0, h1,     h1q,     N, tid, base, A, idxs);
    grid_barrier(bar, nb, 1);
    layer_body<128, true,  false, true,  false>(h1, h1q, Wt1, h2,     h2q,     N, tid, base, A, idxs);
    grid_barrier(bar, nb, 2);
    layer_body< 64, false, true,  false, false>(h2, h2q, Wt2, logits, nullptr, N, tid, base, A, idxs);
}

extern "C" void kernel_launch(void* const* d_in, const int* in_sizes, int n_in,
                              void* d_out, int out_size, void* d_ws, size_t ws_size,
                              hipStream_t stream) {
    int N = 50000;

    const float* x   = (const float*)d_in[0];
    const int*   adj = (const int*)  d_in[1];
    const float* W0  = (const float*)d_in[2];
    const float* W1  = (const float*)d_in[3];
    const float* W2  = (const float*)d_in[4];
    float* logits = (float*)d_out;

    char* ws = (char*)d_ws;
    unsigned short* h1  = (unsigned short*)(ws);                     // 12.8 MB
    unsigned short* h2  = (unsigned short*)(ws + 12800000);          // 12.8 MB
    unsigned char*  xq  = (unsigned char*) (ws + 25600000);          // 6.4 MB
    unsigned char*  h1q = (unsigned char*) (ws + 32000000);          // 6.4 MB
    unsigned char*  h2q = (unsigned char*) (ws + 38400000);          // 6.4 MB
    unsigned short* Wt0 = (unsigned short*)(ws + 44800000);          // 64 KB
    unsigned short* Wt1 = (unsigned short*)(ws + 44800000 + 65536);  // 64 KB
    unsigned short* Wt2 = (unsigned short*)(ws + 44800000 + 131072); // 32 KB
    unsigned int*   bar = (unsigned int*)  (ws + 45200000);          // 512 B barrier state

    // zero barrier state (graph-capturable, deterministic per replay)
    hipMemsetAsync(bar, 0, 512, stream);

    fused_sage<<<NT, 256, 0, stream>>>(x, adj, W0, W1, W2, xq,
                                       h1, h1q, h2, h2q, Wt0, Wt1, Wt2,
                                       bar, logits, N);
}

// Round 10
// 330.820 us; speedup vs baseline: 1.5765x; 1.5765x over previous
//
#include <hip/hip_runtime.h>

// GraphSAGE forward, 3 layers. R10 = R9 persistent kernel, but the grid
// barrier polls with RELAXED loads (no per-iteration L2 invalidate) and
// issues exactly ONE acquire after the flag flips. R9's acquire-in-loop
// emitted buffer_inv per poll -> L2 invalidate storm -> 547us.
// Residency proof: LDS 38912 B/block -> 4 blocks/CU; VGPR<=128 (bounds 256,4);
// 256CU*4=1024 >= 782 blocks, all resident -> barrier deadlock-free.

#define KNBR 16
#define MT   64
#define LDA  272
#define NT   782     // tiles = ceil(50000/64)

typedef __attribute__((ext_vector_type(8))) short short8;
typedef __attribute__((ext_vector_type(4))) float f32x4;
typedef __attribute__((ext_vector_type(2))) float f32x2;

__device__ inline unsigned short f2bf(float f) {
    union { float f; unsigned int i; } c; c.f = f;
    unsigned int u = c.i;
    u += 0x7FFFu + ((u >> 16) & 1u);   // RNE
    return (unsigned short)(u >> 16);
}
__device__ inline unsigned char f2fp8(float v) {
    return (unsigned char)(__builtin_amdgcn_cvt_pk_fp8_f32(v, v, 0, false) & 0xFF);
}

// one-shot grid barrier, slot in [0,3). bar zeroed by hipMemsetAsync pre-launch.
// Publisher: fetch_add ACQ_REL (one wbl2). Waiter: RELAXED poll (no cache op),
// then ONE acquire load after flag flips (one buffer_inv).
__device__ __forceinline__ void grid_barrier(unsigned int* bar, int nblocks, int slot) {
    __syncthreads();
    if (threadIdx.x == 0) {
        unsigned int* cnt  = bar + slot * 32;        // 128B apart
        unsigned int* flag = cnt + 16;
        const unsigned int v =
            __hip_atomic_fetch_add(cnt, 1u, __ATOMIC_ACQ_REL, __HIP_MEMORY_SCOPE_AGENT);
        if (v == (unsigned int)(nblocks - 1)) {
            __hip_atomic_store(flag, 1u, __ATOMIC_RELEASE, __HIP_MEMORY_SCOPE_AGENT);
        } else {
            while (__hip_atomic_load(flag, __ATOMIC_RELAXED, __HIP_MEMORY_SCOPE_AGENT) == 0u)
                __builtin_amdgcn_s_sleep(8);
            (void)__hip_atomic_load(flag, __ATOMIC_ACQUIRE, __HIP_MEMORY_SCOPE_AGENT);
        }
    }
    __syncthreads();
}

// ---------------- per-layer device body (R7-proven) ----------------

template<int FO, bool RELU, bool OUTF32, bool WRITEQ, bool INF32>
__device__ __forceinline__
void layer_body(const void* __restrict__ hself,
                const unsigned char* __restrict__ hq,
                const unsigned short* __restrict__ Wt,
                void* __restrict__ outp,
                unsigned char* __restrict__ outq,
                int N, int tid, int base,
                unsigned short (*A)[LDA], const int (*idxs)[KNBR])
{
    // ---- phase 1: fp8 gather, node-pair MLP; self row -> bf16 LDS ----
    {
        const int lane16 = tid & 15;
        const int grp    = tid >> 4;
        const int f0     = lane16 * 8;
        #pragma unroll
        for (int i = 0; i < 2; ++i) {
            const int lnA = grp * 4 + i * 2;
            const int lnB = lnA + 1;
            int nA = base + lnA; if (nA >= N) nA = N - 1;
            int nB = base + lnB; if (nB >= N) nB = N - 1;

            if (INF32) {
                const float* xf = (const float*)hself;
                const float4 a0 = *reinterpret_cast<const float4*>(&xf[(size_t)nA * 128 + f0]);
                const float4 a1 = *reinterpret_cast<const float4*>(&xf[(size_t)nA * 128 + f0 + 4]);
                const float4 b0 = *reinterpret_cast<const float4*>(&xf[(size_t)nB * 128 + f0]);
                const float4 b1 = *reinterpret_cast<const float4*>(&xf[(size_t)nB * 128 + f0 + 4]);
                uint4 oa, ob;
                oa.x = (unsigned int)f2bf(a0.x) | ((unsigned int)f2bf(a0.y) << 16);
                oa.y = (unsigned int)f2bf(a0.z) | ((unsigned int)f2bf(a0.w) << 16);
                oa.z = (unsigned int)f2bf(a1.x) | ((unsigned int)f2bf(a1.y) << 16);
                oa.w = (unsigned int)f2bf(a1.z) | ((unsigned int)f2bf(a1.w) << 16);
                ob.x = (unsigned int)f2bf(b0.x) | ((unsigned int)f2bf(b0.y) << 16);
                ob.y = (unsigned int)f2bf(b0.z) | ((unsigned int)f2bf(b0.w) << 16);
                ob.z = (unsigned int)f2bf(b1.x) | ((unsigned int)f2bf(b1.y) << 16);
                ob.w = (unsigned int)f2bf(b1.z) | ((unsigned int)f2bf(b1.w) << 16);
                *reinterpret_cast<uint4*>(&A[lnA][f0]) = oa;
                *reinterpret_cast<uint4*>(&A[lnB][f0]) = ob;
            } else {
                const unsigned short* hb = (const unsigned short*)hself;
                *reinterpret_cast<uint4*>(&A[lnA][f0]) =
                    *reinterpret_cast<const uint4*>(&hb[(size_t)nA * 128 + f0]);
                *reinterpret_cast<uint4*>(&A[lnB][f0]) =
                    *reinterpret_cast<const uint4*>(&hb[(size_t)nB * 128 + f0]);
            }

            uint2 va[KNBR], vb[KNBR];
            #pragma unroll
            for (int k = 0; k < KNBR; ++k)
                va[k] = *reinterpret_cast<const uint2*>(&hq[(size_t)idxs[lnA][k] * 128 + f0]);
            #pragma unroll
            for (int k = 0; k < KNBR; ++k)
                vb[k] = *reinterpret_cast<const uint2*>(&hq[(size_t)idxs[lnB][k] * 128 + f0]);

            f32x2 a01 = {0.f,0.f}, a23 = {0.f,0.f}, a45 = {0.f,0.f}, a67 = {0.f,0.f};
            #pragma unroll
            for (int k = 0; k < KNBR; ++k) {
                a01 += __builtin_amdgcn_cvt_pk_f32_fp8(va[k].x, false);
                a23 += __builtin_amdgcn_cvt_pk_f32_fp8(va[k].x, true);
                a45 += __builtin_amdgcn_cvt_pk_f32_fp8(va[k].y, false);
                a67 += __builtin_amdgcn_cvt_pk_f32_fp8(va[k].y, true);
            }
            uint4 pA;
            pA.x = (unsigned int)f2bf(a01.x * 0.0625f) | ((unsigned int)f2bf(a01.y * 0.0625f) << 16);
            pA.y = (unsigned int)f2bf(a23.x * 0.0625f) | ((unsigned int)f2bf(a23.y * 0.0625f) << 16);
            pA.z = (unsigned int)f2bf(a45.x * 0.0625f) | ((unsigned int)f2bf(a45.y * 0.0625f) << 16);
            pA.w = (unsigned int)f2bf(a67.x * 0.0625f) | ((unsigned int)f2bf(a67.y * 0.0625f) << 16);
            *reinterpret_cast<uint4*>(&A[lnA][128 + f0]) = pA;

            f32x2 b01 = {0.f,0.f}, b23 = {0.f,0.f}, b45 = {0.f,0.f}, b67 = {0.f,0.f};
            #pragma unroll
            for (int k = 0; k < KNBR; ++k) {
                b01 += __builtin_amdgcn_cvt_pk_f32_fp8(vb[k].x, false);
                b23 += __builtin_amdgcn_cvt_pk_f32_fp8(vb[k].x, true);
                b45 += __builtin_amdgcn_cvt_pk_f32_fp8(vb[k].y, false);
                b67 += __builtin_amdgcn_cvt_pk_f32_fp8(vb[k].y, true);
            }
            uint4 pB;
            pB.x = (unsigned int)f2bf(b01.x * 0.0625f) | ((unsigned int)f2bf(b01.y * 0.0625f) << 16);
            pB.y = (unsigned int)f2bf(b23.x * 0.0625f) | ((unsigned int)f2bf(b23.y * 0.0625f) << 16);
            pB.z = (unsigned int)f2bf(b45.x * 0.0625f) | ((unsigned int)f2bf(b45.y * 0.0625f) << 16);
            pB.w = (unsigned int)f2bf(b67.x * 0.0625f) | ((unsigned int)f2bf(b67.y * 0.0625f) << 16);
            *reinterpret_cast<uint4*>(&A[lnB][128 + f0]) = pB;
        }
    }
    __syncthreads();

    // ---- phase 2: [64 x 256] @ [256 x FO] via mfma_f32_16x16x32_bf16 ----
    {
        constexpr int NCT = FO / 64;
        const int wv  = tid >> 6;
        const int l   = tid & 63;
        const int l15 = l & 15;
        const int kg  = l >> 4;

        f32x4 acc[4][NCT];
        #pragma unroll
        for (int rt = 0; rt < 4; ++rt)
            #pragma unroll
            for (int c = 0; c < NCT; ++c)
                acc[rt][c] = (f32x4){0.f, 0.f, 0.f, 0.f};

        const unsigned short* wbase[NCT];
        #pragma unroll
        for (int c = 0; c < NCT; ++c) {
            const int col = (wv * NCT + c) * 16 + l15;
            wbase[c] = Wt + (size_t)col * 256 + kg * 8;
        }

        #pragma unroll
        for (int ks = 0; ks < 8; ++ks) {
            short8 b[NCT];
            #pragma unroll
            for (int c = 0; c < NCT; ++c)
                b[c] = *reinterpret_cast<const short8*>(wbase[c] + ks * 32);
            #pragma unroll
            for (int rt = 0; rt < 4; ++rt) {
                const short8 a = *reinterpret_cast<const short8*>(&A[rt * 16 + l15][ks * 32 + kg * 8]);
                #pragma unroll
                for (int c = 0; c < NCT; ++c)
                    acc[rt][c] = __builtin_amdgcn_mfma_f32_16x16x32_bf16(a, b[c], acc[rt][c], 0, 0, 0);
            }
        }

        #pragma unroll
        for (int rt = 0; rt < 4; ++rt) {
            #pragma unroll
            for (int c = 0; c < NCT; ++c) {
                const int col = (wv * NCT + c) * 16 + l15;
                #pragma unroll
                for (int r = 0; r < 4; ++r) {
                    const int row = rt * 16 + kg * 4 + r;
                    const int n   = base + row;
                    if (n < N) {
                        float v = acc[rt][c][r];
                        if (RELU) v = fmaxf(v, 0.f);
                        if (OUTF32)
                            reinterpret_cast<float*>(outp)[(size_t)n * FO + col] = v;
                        else
                            reinterpret_cast<unsigned short*>(outp)[(size_t)n * FO + col] = f2bf(v);
                        if (WRITEQ)
                            outq[(size_t)n * FO + col] = f2fp8(v);
                    }
                }
            }
        }
    }
}

// ---------------- the single persistent kernel ----------------

__global__ __launch_bounds__(256, 4)
void fused_sage(const float* __restrict__ x, const int* __restrict__ adj,
                const float* __restrict__ W0, const float* __restrict__ W1,
                const float* __restrict__ W2,
                unsigned char* __restrict__ xq,
                unsigned short* __restrict__ h1, unsigned char* __restrict__ h1q,
                unsigned short* __restrict__ h2, unsigned char* __restrict__ h2q,
                unsigned short* __restrict__ Wt0, unsigned short* __restrict__ Wt1,
                unsigned short* __restrict__ Wt2,
                unsigned int* __restrict__ bar,
                float* __restrict__ logits, int N)
{
    __shared__ unsigned short A[MT][LDA];
    __shared__ int idxs[MT][KNBR];

    const int tid     = threadIdx.x;
    const int base    = blockIdx.x * MT;
    const int gid     = blockIdx.x * 256 + tid;
    const int gstride = gridDim.x * 256;
    const int nb      = gridDim.x;

    // ---- prep A: x -> fp8 xq (grid-stride) ----
    {
        const int total4 = N * 128 / 4;
        for (int i = gid; i < total4; i += gstride) {
            const float4 v = reinterpret_cast<const float4*>(x)[i];
            unsigned int q;
            q = __builtin_amdgcn_cvt_pk_fp8_f32(v.x, v.y, 0, false);
            q = __builtin_amdgcn_cvt_pk_fp8_f32(v.z, v.w, q, true);
            reinterpret_cast<unsigned int*>(xq)[i] = q;
        }
    }
    // ---- prep B: W transposes -> bf16 ----
    for (int id = gid; id < 81920; id += gstride) {
        const float* W; unsigned short* Wt; int FO; int loc;
        if (id < 32768)      { W = W0; Wt = Wt0; FO = 128; loc = id; }
        else if (id < 65536) { W = W1; Wt = Wt1; FO = 128; loc = id - 32768; }
        else                 { W = W2; Wt = Wt2; FO = 64;  loc = id - 65536; }
        const int j = loc >> 8;
        const int k = loc & 255;
        Wt[loc] = f2bf(W[k * FO + j]);
    }
    // ---- prep C: neighbor indices (layer-invariant) -> LDS ----
    {
        const int nn = tid & 63;
        const int q  = tid >> 6;
        int n = base + nn; if (n >= N) n = N - 1;
        #pragma unroll
        for (int rep = 0; rep < 4; ++rep) {
            const int kk = rep * 4 + q;
            idxs[nn][kk] = adj[(size_t)kk * N + n];
        }
    }

    grid_barrier(bar, nb, 0);
    layer_body<128, true,  false, true,  true >(x,  xq,  Wt0, h1,     h1q,     N, tid, base, A, idxs);
    grid_barrier(bar, nb, 1);
    layer_body<128, true,  false, true,  false>(h1, h1q, Wt1, h2,     h2q,     N, tid, base, A, idxs);
    grid_barrier(bar, nb, 2);
    layer_body< 64, false, true,  false, false>(h2, h2q, Wt2, logits, nullptr, N, tid, base, A, idxs);
}

extern "C" void kernel_launch(void* const* d_in, const int* in_sizes, int n_in,
                              void* d_out, int out_size, void* d_ws, size_t ws_size,
                              hipStream_t stream) {
    int N = 50000;

    const float* x   = (const float*)d_in[0];
    const int*   adj = (const int*)  d_in[1];
    const float* W0  = (const float*)d_in[2];
    const float* W1  = (const float*)d_in[3];
    const float* W2  = (const float*)d_in[4];
    float* logits = (float*)d_out;

    char* ws = (char*)d_ws;
    unsigned short* h1  = (unsigned short*)(ws);                     // 12.8 MB
    unsigned short* h2  = (unsigned short*)(ws + 12800000);          // 12.8 MB
    unsigned char*  xq  = (unsigned char*) (ws + 25600000);          // 6.4 MB
    unsigned char*  h1q = (unsigned char*) (ws + 32000000);          // 6.4 MB
    unsigned char*  h2q = (unsigned char*) (ws + 38400000);          // 6.4 MB
    unsigned short* Wt0 = (unsigned short*)(ws + 44800000);          // 64 KB
    unsigned short* Wt1 = (unsigned short*)(ws + 44800000 + 65536);  // 64 KB
    unsigned short* Wt2 = (unsigned short*)(ws + 44800000 + 131072); // 32 KB
    unsigned int*   bar = (unsigned int*)  (ws + 45200000);          // 512 B barrier state

    // zero barrier state (graph-capturable, deterministic per replay)
    hipMemsetAsync(bar, 0, 512, stream);

    fused_sage<<<NT, 256, 0, stream>>>(x, adj, W0, W1, W2, xq,
                                       h1, h1q, h2, h2q, Wt0, Wt1, Wt2,
                                       bar, logits, N);
}

// Round 11
// 316.542 us; speedup vs baseline: 1.6476x; 1.0451x over previous
//
#include <hip/hip_runtime.h>

// GraphSAGE forward, 3 layers. R11 = R10 persistent kernel with corrected
// barrier cache semantics: RELEASE at arrival (writeback only, keeps L2
// contents), single ACQUIRE per block at exit (clustered invalidate after
// the flag flips). R10's ACQ_REL arrival invalidated L2 mid-epoch -> 330us.
// Residency proof: LDS 38912 B/block -> 4 blocks/CU; VGPR<=128 (bounds 256,4);
// 256CU*4=1024 >= 782 blocks, all resident -> barrier deadlock-free.

#define KNBR 16
#define MT   64
#define LDA  272
#define NT   782     // tiles = ceil(50000/64)

typedef __attribute__((ext_vector_type(8))) short short8;
typedef __attribute__((ext_vector_type(4))) float f32x4;
typedef __attribute__((ext_vector_type(2))) float f32x2;

__device__ inline unsigned short f2bf(float f) {
    union { float f; unsigned int i; } c; c.f = f;
    unsigned int u = c.i;
    u += 0x7FFFu + ((u >> 16) & 1u);   // RNE
    return (unsigned short)(u >> 16);
}
__device__ inline unsigned char f2fp8(float v) {
    return (unsigned char)(__builtin_amdgcn_cvt_pk_fp8_f32(v, v, 0, false) & 0xFF);
}

// one-shot grid barrier, slot in [0,3). bar zeroed by hipMemsetAsync pre-launch.
// Arrival: fetch_add RELEASE (buffer_wbl2 writeback, L2 lines stay valid).
// Poll: RELAXED (no cache op). Exit: ONE acquire load per block (clustered
// buffer_inv after flag set -- data refresh the next layer needs anyway).
__device__ __forceinline__ void grid_barrier(unsigned int* bar, int nblocks, int slot) {
    __syncthreads();
    if (threadIdx.x == 0) {
        unsigned int* cnt  = bar + slot * 32;        // 128B apart
        unsigned int* flag = cnt + 16;
        const unsigned int v =
            __hip_atomic_fetch_add(cnt, 1u, __ATOMIC_RELEASE, __HIP_MEMORY_SCOPE_AGENT);
        if (v == (unsigned int)(nblocks - 1)) {
            __hip_atomic_store(flag, 1u, __ATOMIC_RELEASE, __HIP_MEMORY_SCOPE_AGENT);
        } else {
            while (__hip_atomic_load(flag, __ATOMIC_RELAXED, __HIP_MEMORY_SCOPE_AGENT) == 0u)
                __builtin_amdgcn_s_sleep(16);
        }
        // every block (incl. flag-setter): exactly one acquire at exit
        (void)__hip_atomic_load(flag, __ATOMIC_ACQUIRE, __HIP_MEMORY_SCOPE_AGENT);
    }
    __syncthreads();
}

// ---------------- per-layer device body (R7-proven) ----------------

template<int FO, bool RELU, bool OUTF32, bool WRITEQ, bool INF32>
__device__ __forceinline__
void layer_body(const void* __restrict__ hself,
                const unsigned char* __restrict__ hq,
                const unsigned short* __restrict__ Wt,
                void* __restrict__ outp,
                unsigned char* __restrict__ outq,
                int N, int tid, int base,
                unsigned short (*A)[LDA], const int (*idxs)[KNBR])
{
    // ---- phase 1: fp8 gather, node-pair MLP; self row -> bf16 LDS ----
    {
        const int lane16 = tid & 15;
        const int grp    = tid >> 4;
        const int f0     = lane16 * 8;
        #pragma unroll
        for (int i = 0; i < 2; ++i) {
            const int lnA = grp * 4 + i * 2;
            const int lnB = lnA + 1;
            int nA = base + lnA; if (nA >= N) nA = N - 1;
            int nB = base + lnB; if (nB >= N) nB = N - 1;

            if (INF32) {
                const float* xf = (const float*)hself;
                const float4 a0 = *reinterpret_cast<const float4*>(&xf[(size_t)nA * 128 + f0]);
                const float4 a1 = *reinterpret_cast<const float4*>(&xf[(size_t)nA * 128 + f0 + 4]);
                const float4 b0 = *reinterpret_cast<const float4*>(&xf[(size_t)nB * 128 + f0]);
                const float4 b1 = *reinterpret_cast<const float4*>(&xf[(size_t)nB * 128 + f0 + 4]);
                uint4 oa, ob;
                oa.x = (unsigned int)f2bf(a0.x) | ((unsigned int)f2bf(a0.y) << 16);
                oa.y = (unsigned int)f2bf(a0.z) | ((unsigned int)f2bf(a0.w) << 16);
                oa.z = (unsigned int)f2bf(a1.x) | ((unsigned int)f2bf(a1.y) << 16);
                oa.w = (unsigned int)f2bf(a1.z) | ((unsigned int)f2bf(a1.w) << 16);
                ob.x = (unsigned int)f2bf(b0.x) | ((unsigned int)f2bf(b0.y) << 16);
                ob.y = (unsigned int)f2bf(b0.z) | ((unsigned int)f2bf(b0.w) << 16);
                ob.z = (unsigned int)f2bf(b1.x) | ((unsigned int)f2bf(b1.y) << 16);
                ob.w = (unsigned int)f2bf(b1.z) | ((unsigned int)f2bf(b1.w) << 16);
                *reinterpret_cast<uint4*>(&A[lnA][f0]) = oa;
                *reinterpret_cast<uint4*>(&A[lnB][f0]) = ob;
            } else {
                const unsigned short* hb = (const unsigned short*)hself;
                *reinterpret_cast<uint4*>(&A[lnA][f0]) =
                    *reinterpret_cast<const uint4*>(&hb[(size_t)nA * 128 + f0]);
                *reinterpret_cast<uint4*>(&A[lnB][f0]) =
                    *reinterpret_cast<const uint4*>(&hb[(size_t)nB * 128 + f0]);
            }

            uint2 va[KNBR], vb[KNBR];
            #pragma unroll
            for (int k = 0; k < KNBR; ++k)
                va[k] = *reinterpret_cast<const uint2*>(&hq[(size_t)idxs[lnA][k] * 128 + f0]);
            #pragma unroll
            for (int k = 0; k < KNBR; ++k)
                vb[k] = *reinterpret_cast<const uint2*>(&hq[(size_t)idxs[lnB][k] * 128 + f0]);

            f32x2 a01 = {0.f,0.f}, a23 = {0.f,0.f}, a45 = {0.f,0.f}, a67 = {0.f,0.f};
            #pragma unroll
            for (int k = 0; k < KNBR; ++k) {
                a01 += __builtin_amdgcn_cvt_pk_f32_fp8(va[k].x, false);
                a23 += __builtin_amdgcn_cvt_pk_f32_fp8(va[k].x, true);
                a45 += __builtin_amdgcn_cvt_pk_f32_fp8(va[k].y, false);
                a67 += __builtin_amdgcn_cvt_pk_f32_fp8(va[k].y, true);
            }
            uint4 pA;
            pA.x = (unsigned int)f2bf(a01.x * 0.0625f) | ((unsigned int)f2bf(a01.y * 0.0625f) << 16);
            pA.y = (unsigned int)f2bf(a23.x * 0.0625f) | ((unsigned int)f2bf(a23.y * 0.0625f) << 16);
            pA.z = (unsigned int)f2bf(a45.x * 0.0625f) | ((unsigned int)f2bf(a45.y * 0.0625f) << 16);
            pA.w = (unsigned int)f2bf(a67.x * 0.0625f) | ((unsigned int)f2bf(a67.y * 0.0625f) << 16);
            *reinterpret_cast<uint4*>(&A[lnA][128 + f0]) = pA;

            f32x2 b01 = {0.f,0.f}, b23 = {0.f,0.f}, b45 = {0.f,0.f}, b67 = {0.f,0.f};
            #pragma unroll
            for (int k = 0; k < KNBR; ++k) {
                b01 += __builtin_amdgcn_cvt_pk_f32_fp8(vb[k].x, false);
                b23 += __builtin_amdgcn_cvt_pk_f32_fp8(vb[k].x, true);
                b45 += __builtin_amdgcn_cvt_pk_f32_fp8(vb[k].y, false);
                b67 += __builtin_amdgcn_cvt_pk_f32_fp8(vb[k].y, true);
            }
            uint4 pB;
            pB.x = (unsigned int)f2bf(b01.x * 0.0625f) | ((unsigned int)f2bf(b01.y * 0.0625f) << 16);
            pB.y = (unsigned int)f2bf(b23.x * 0.0625f) | ((unsigned int)f2bf(b23.y * 0.0625f) << 16);
            pB.z = (unsigned int)f2bf(b45.x * 0.0625f) | ((unsigned int)f2bf(b45.y * 0.0625f) << 16);
            pB.w = (unsigned int)f2bf(b67.x * 0.0625f) | ((unsigned int)f2bf(b67.y * 0.0625f) << 16);
            *reinterpret_cast<uint4*>(&A[lnB][128 + f0]) = pB;
        }
    }
    __syncthreads();

    // ---- phase 2: [64 x 256] @ [256 x FO] via mfma_f32_16x16x32_bf16 ----
    {
        constexpr int NCT = FO / 64;
        const int wv  = tid >> 6;
        const int l   = tid & 63;
        const int l15 = l & 15;
        const int kg  = l >> 4;

        f32x4 acc[4][NCT];
        #pragma unroll
        for (int rt = 0; rt < 4; ++rt)
            #pragma unroll
            for (int c = 0; c < NCT; ++c)
                acc[rt][c] = (f32x4){0.f, 0.f, 0.f, 0.f};

        const unsigned short* wbase[NCT];
        #pragma unroll
        for (int c = 0; c < NCT; ++c) {
            const int col = (wv * NCT + c) * 16 + l15;
            wbase[c] = Wt + (size_t)col * 256 + kg * 8;
        }

        #pragma unroll
        for (int ks = 0; ks < 8; ++ks) {
            short8 b[NCT];
            #pragma unroll
            for (int c = 0; c < NCT; ++c)
                b[c] = *reinterpret_cast<const short8*>(wbase[c] + ks * 32);
            #pragma unroll
            for (int rt = 0; rt < 4; ++rt) {
                const short8 a = *reinterpret_cast<const short8*>(&A[rt * 16 + l15][ks * 32 + kg * 8]);
                #pragma unroll
                for (int c = 0; c < NCT; ++c)
                    acc[rt][c] = __builtin_amdgcn_mfma_f32_16x16x32_bf16(a, b[c], acc[rt][c], 0, 0, 0);
            }
        }

        #pragma unroll
        for (int rt = 0; rt < 4; ++rt) {
            #pragma unroll
            for (int c = 0; c < NCT; ++c) {
                const int col = (wv * NCT + c) * 16 + l15;
                #pragma unroll
                for (int r = 0; r < 4; ++r) {
                    const int row = rt * 16 + kg * 4 + r;
                    const int n   = base + row;
                    if (n < N) {
                        float v = acc[rt][c][r];
                        if (RELU) v = fmaxf(v, 0.f);
                        if (OUTF32)
                            reinterpret_cast<float*>(outp)[(size_t)n * FO + col] = v;
                        else
                            reinterpret_cast<unsigned short*>(outp)[(size_t)n * FO + col] = f2bf(v);
                        if (WRITEQ)
                            outq[(size_t)n * FO + col] = f2fp8(v);
                    }
                }
            }
        }
    }
}

// ---------------- the single persistent kernel ----------------

__global__ __launch_bounds__(256, 4)
void fused_sage(const float* __restrict__ x, const int* __restrict__ adj,
                const float* __restrict__ W0, const float* __restrict__ W1,
                const float* __restrict__ W2,
                unsigned char* __restrict__ xq,
                unsigned short* __restrict__ h1, unsigned char* __restrict__ h1q,
                unsigned short* __restrict__ h2, unsigned char* __restrict__ h2q,
                unsigned short* __restrict__ Wt0, unsigned short* __restrict__ Wt1,
                unsigned short* __restrict__ Wt2,
                unsigned int* __restrict__ bar,
                float* __restrict__ logits, int N)
{
    __shared__ unsigned short A[MT][LDA];
    __shared__ int idxs[MT][KNBR];

    const int tid     = threadIdx.x;
    const int base    = blockIdx.x * MT;
    const int gid     = blockIdx.x * 256 + tid;
    const int gstride = gridDim.x * 256;
    const int nb      = gridDim.x;

    // ---- prep A: x -> fp8 xq (grid-stride) ----
    {
        const int total4 = N * 128 / 4;
        for (int i = gid; i < total4; i += gstride) {
            const float4 v = reinterpret_cast<const float4*>(x)[i];
            unsigned int q;
            q = __builtin_amdgcn_cvt_pk_fp8_f32(v.x, v.y, 0, false);
            q = __builtin_amdgcn_cvt_pk_fp8_f32(v.z, v.w, q, true);
            reinterpret_cast<unsigned int*>(xq)[i] = q;
        }
    }
    // ---- prep B: W transposes -> bf16 ----
    for (int id = gid; id < 81920; id += gstride) {
        const float* W; unsigned short* Wt; int FO; int loc;
        if (id < 32768)      { W = W0; Wt = Wt0; FO = 128; loc = id; }
        else if (id < 65536) { W = W1; Wt = Wt1; FO = 128; loc = id - 32768; }
        else                 { W = W2; Wt = Wt2; FO = 64;  loc = id - 65536; }
        const int j = loc >> 8;
        const int k = loc & 255;
        Wt[loc] = f2bf(W[k * FO + j]);
    }
    // ---- prep C: neighbor indices (layer-invariant) -> LDS ----
    {
        const int nn = tid & 63;
        const int q  = tid >> 6;
        int n = base + nn; if (n >= N) n = N - 1;
        #pragma unroll
        for (int rep = 0; rep < 4; ++rep) {
            const int kk = rep * 4 + q;
            idxs[nn][kk] = adj[(size_t)kk * N + n];
        }
    }

    grid_barrier(bar, nb, 0);
    layer_body<128, true,  false, true,  true >(x,  xq,  Wt0, h1,     h1q,     N, tid, base, A, idxs);
    grid_barrier(bar, nb, 1);
    layer_body<128, true,  false, true,  false>(h1, h1q, Wt1, h2,     h2q,     N, tid, base, A, idxs);
    grid_barrier(bar, nb, 2);
    layer_body< 64, false, true,  false, false>(h2, h2q, Wt2, logits, nullptr, N, tid, base, A, idxs);
}

extern "C" void kernel_launch(void* const* d_in, const int* in_sizes, int n_in,
                              void* d_out, int out_size, void* d_ws, size_t ws_size,
                              hipStream_t stream) {
    int N = 50000;

    const float* x   = (const float*)d_in[0];
    const int*   adj = (const int*)  d_in[1];
    const float* W0  = (const float*)d_in[2];
    const float* W1  = (const float*)d_in[3];
    const float* W2  = (const float*)d_in[4];
    float* logits = (float*)d_out;

    char* ws = (char*)d_ws;
    unsigned short* h1  = (unsigned short*)(ws);                     // 12.8 MB
    unsigned short* h2  = (unsigned short*)(ws + 12800000);          // 12.8 MB
    unsigned char*  xq  = (unsigned char*) (ws + 25600000);          // 6.4 MB
    unsigned char*  h1q = (unsigned char*) (ws + 32000000);          // 6.4 MB
    unsigned char*  h2q = (unsigned char*) (ws + 38400000);          // 6.4 MB
    unsigned short* Wt0 = (unsigned short*)(ws + 44800000);          // 64 KB
    unsigned short* Wt1 = (unsigned short*)(ws + 44800000 + 65536);  // 64 KB
    unsigned short* Wt2 = (unsigned short*)(ws + 44800000 + 131072); // 32 KB
    unsigned int*   bar = (unsigned int*)  (ws + 45200000);          // 512 B barrier state

    // zero barrier state (graph-capturable, deterministic per replay)
    hipMemsetAsync(bar, 0, 512, stream);

    fused_sage<<<NT, 256, 0, stream>>>(x, adj, W0, W1, W2, xq,
                                       h1, h1q, h2, h2q, Wt0, Wt1, Wt2,
                                       bar, logits, N);
}

// Round 12
// 81.652 us; speedup vs baseline: 6.3873x; 3.8767x over previous
//
#include <hip/hip_runtime.h>

// GraphSAGE forward, 3 layers. R12 = revert to R7 (83.5us proven best:
// 5-dispatch, fused per-layer gather+MFMA kernel, fp8 gather path) +
// (a) single merged prep kernel, (b) layer-1 self rows staged from f32 x
// directly (xb buffer eliminated). Persistent-kernel path abandoned:
// software grid barriers cost >=70us/epoch on 8-XCD CDNA4 (R9-R11).

#define KNBR 16
#define MT   64
#define LDA  272

typedef __attribute__((ext_vector_type(8))) short short8;
typedef __attribute__((ext_vector_type(4))) float f32x4;
typedef __attribute__((ext_vector_type(2))) float f32x2;

__device__ inline unsigned short f2bf(float f) {
    union { float f; unsigned int i; } c; c.f = f;
    unsigned int u = c.i;
    u += 0x7FFFu + ((u >> 16) & 1u);   // RNE
    return (unsigned short)(u >> 16);
}
__device__ inline unsigned char f2fp8(float v) {
    return (unsigned char)(__builtin_amdgcn_cvt_pk_fp8_f32(v, v, 0, false) & 0xFF);
}

// ---------------- merged prep: x -> fp8 xq, W0/W1/W2 -> bf16 transposed ----------------

__global__ __launch_bounds__(256)
void prep_kernel(const float* __restrict__ x, unsigned char* __restrict__ xq, int total4,
                 const float* __restrict__ W0, const float* __restrict__ W1,
                 const float* __restrict__ W2,
                 unsigned short* __restrict__ Wt0, unsigned short* __restrict__ Wt1,
                 unsigned short* __restrict__ Wt2) {
    const int gid = blockIdx.x * 256 + threadIdx.x;
    if (gid < total4) {
        const float4 v = reinterpret_cast<const float4*>(x)[gid];
        unsigned int q;
        q = __builtin_amdgcn_cvt_pk_fp8_f32(v.x, v.y, 0, false);
        q = __builtin_amdgcn_cvt_pk_fp8_f32(v.z, v.w, q, true);
        reinterpret_cast<unsigned int*>(xq)[gid] = q;
    }
    if (gid < 81920) {
        const float* W; unsigned short* Wt; int FO; int loc;
        if (gid < 32768)      { W = W0; Wt = Wt0; FO = 128; loc = gid; }
        else if (gid < 65536) { W = W1; Wt = Wt1; FO = 128; loc = gid - 32768; }
        else                  { W = W2; Wt = Wt2; FO = 64;  loc = gid - 65536; }
        const int j = loc >> 8;
        const int k = loc & 255;
        Wt[loc] = f2bf(W[k * FO + j]);
    }
}

// ---------------- layer kernel (R7-proven body, +INF32 self staging) ----------------

template<int FO, bool RELU, bool OUTF32, bool WRITEQ, bool INF32>
__global__ __launch_bounds__(256, 4)
void sage_layer(const void* __restrict__ hself,         // [N][128] bf16 (or f32 if INF32)
                const unsigned char*  __restrict__ hq,  // [N][128] fp8 (gather path)
                const int* __restrict__ adj,            // [16][N]
                const unsigned short* __restrict__ Wt,  // [FO][256] bf16 (transposed W)
                void* __restrict__ outp,                // [N][FO] bf16 or f32
                unsigned char* __restrict__ outq,       // [N][FO] fp8 shadow (if WRITEQ)
                int N)
{
    __shared__ unsigned short A[MT][LDA];   // hcat tile: [0..127]=self, [128..255]=agg
    __shared__ int idxs[MT][KNBR];

    const int tid  = threadIdx.x;
    const int base = blockIdx.x * MT;

    // ---- phase 0: neighbor indices -> LDS (coalesced over n) ----
    {
        const int nn = tid & 63;
        const int q  = tid >> 6;
        int n = base + nn; if (n >= N) n = N - 1;
        #pragma unroll
        for (int rep = 0; rep < 4; ++rep) {
            const int kk = rep * 4 + q;
            idxs[nn][kk] = adj[(size_t)kk * N + n];
        }
    }
    __syncthreads();

    // ---- phase 1: fp8 gather, node-pair MLP; self row -> bf16 LDS ----
    {
        const int lane16 = tid & 15;
        const int grp    = tid >> 4;
        const int f0     = lane16 * 8;
        #pragma unroll
        for (int i = 0; i < 2; ++i) {
            const int lnA = grp * 4 + i * 2;
            const int lnB = lnA + 1;
            int nA = base + lnA; if (nA >= N) nA = N - 1;
            int nB = base + lnB; if (nB >= N) nB = N - 1;

            if (INF32) {
                const float* xf = (const float*)hself;
                const float4 a0 = *reinterpret_cast<const float4*>(&xf[(size_t)nA * 128 + f0]);
                const float4 a1 = *reinterpret_cast<const float4*>(&xf[(size_t)nA * 128 + f0 + 4]);
                const float4 b0 = *reinterpret_cast<const float4*>(&xf[(size_t)nB * 128 + f0]);
                const float4 b1 = *reinterpret_cast<const float4*>(&xf[(size_t)nB * 128 + f0 + 4]);
                uint4 oa, ob;
                oa.x = (unsigned int)f2bf(a0.x) | ((unsigned int)f2bf(a0.y) << 16);
                oa.y = (unsigned int)f2bf(a0.z) | ((unsigned int)f2bf(a0.w) << 16);
                oa.z = (unsigned int)f2bf(a1.x) | ((unsigned int)f2bf(a1.y) << 16);
                oa.w = (unsigned int)f2bf(a1.z) | ((unsigned int)f2bf(a1.w) << 16);
                ob.x = (unsigned int)f2bf(b0.x) | ((unsigned int)f2bf(b0.y) << 16);
                ob.y = (unsigned int)f2bf(b0.z) | ((unsigned int)f2bf(b0.w) << 16);
                ob.z = (unsigned int)f2bf(b1.x) | ((unsigned int)f2bf(b1.y) << 16);
                ob.w = (unsigned int)f2bf(b1.z) | ((unsigned int)f2bf(b1.w) << 16);
                *reinterpret_cast<uint4*>(&A[lnA][f0]) = oa;
                *reinterpret_cast<uint4*>(&A[lnB][f0]) = ob;
            } else {
                const unsigned short* hb = (const unsigned short*)hself;
                *reinterpret_cast<uint4*>(&A[lnA][f0]) =
                    *reinterpret_cast<const uint4*>(&hb[(size_t)nA * 128 + f0]);
                *reinterpret_cast<uint4*>(&A[lnB][f0]) =
                    *reinterpret_cast<const uint4*>(&hb[(size_t)nB * 128 + f0]);
            }

            // issue all 32 gather loads before accumulating (MLP)
            uint2 va[KNBR], vb[KNBR];
            #pragma unroll
            for (int k = 0; k < KNBR; ++k)
                va[k] = *reinterpret_cast<const uint2*>(&hq[(size_t)idxs[lnA][k] * 128 + f0]);
            #pragma unroll
            for (int k = 0; k < KNBR; ++k)
                vb[k] = *reinterpret_cast<const uint2*>(&hq[(size_t)idxs[lnB][k] * 128 + f0]);

            f32x2 a01 = {0.f,0.f}, a23 = {0.f,0.f}, a45 = {0.f,0.f}, a67 = {0.f,0.f};
            #pragma unroll
            for (int k = 0; k < KNBR; ++k) {
                a01 += __builtin_amdgcn_cvt_pk_f32_fp8(va[k].x, false);
                a23 += __builtin_amdgcn_cvt_pk_f32_fp8(va[k].x, true);
                a45 += __builtin_amdgcn_cvt_pk_f32_fp8(va[k].y, false);
                a67 += __builtin_amdgcn_cvt_pk_f32_fp8(va[k].y, true);
            }
            uint4 pA;
            pA.x = (unsigned int)f2bf(a01.x * 0.0625f) | ((unsigned int)f2bf(a01.y * 0.0625f) << 16);
            pA.y = (unsigned int)f2bf(a23.x * 0.0625f) | ((unsigned int)f2bf(a23.y * 0.0625f) << 16);
            pA.z = (unsigned int)f2bf(a45.x * 0.0625f) | ((unsigned int)f2bf(a45.y * 0.0625f) << 16);
            pA.w = (unsigned int)f2bf(a67.x * 0.0625f) | ((unsigned int)f2bf(a67.y * 0.0625f) << 16);
            *reinterpret_cast<uint4*>(&A[lnA][128 + f0]) = pA;

            f32x2 b01 = {0.f,0.f}, b23 = {0.f,0.f}, b45 = {0.f,0.f}, b67 = {0.f,0.f};
            #pragma unroll
            for (int k = 0; k < KNBR; ++k) {
                b01 += __builtin_amdgcn_cvt_pk_f32_fp8(vb[k].x, false);
                b23 += __builtin_amdgcn_cvt_pk_f32_fp8(vb[k].x, true);
                b45 += __builtin_amdgcn_cvt_pk_f32_fp8(vb[k].y, false);
                b67 += __builtin_amdgcn_cvt_pk_f32_fp8(vb[k].y, true);
            }
            uint4 pB;
            pB.x = (unsigned int)f2bf(b01.x * 0.0625f) | ((unsigned int)f2bf(b01.y * 0.0625f) << 16);
            pB.y = (unsigned int)f2bf(b23.x * 0.0625f) | ((unsigned int)f2bf(b23.y * 0.0625f) << 16);
            pB.z = (unsigned int)f2bf(b45.x * 0.0625f) | ((unsigned int)f2bf(b45.y * 0.0625f) << 16);
            pB.w = (unsigned int)f2bf(b67.x * 0.0625f) | ((unsigned int)f2bf(b67.y * 0.0625f) << 16);
            *reinterpret_cast<uint4*>(&A[lnB][128 + f0]) = pB;
        }
    }
    __syncthreads();

    // ---- phase 2: [64 x 256] @ [256 x FO] via mfma_f32_16x16x32_bf16 ----
    {
        constexpr int NCT = FO / 64;
        const int wv  = tid >> 6;
        const int l   = tid & 63;
        const int l15 = l & 15;
        const int kg  = l >> 4;

        f32x4 acc[4][NCT];
        #pragma unroll
        for (int rt = 0; rt < 4; ++rt)
            #pragma unroll
            for (int c = 0; c < NCT; ++c)
                acc[rt][c] = (f32x4){0.f, 0.f, 0.f, 0.f};

        const unsigned short* wbase[NCT];
        #pragma unroll
        for (int c = 0; c < NCT; ++c) {
            const int col = (wv * NCT + c) * 16 + l15;
            wbase[c] = Wt + (size_t)col * 256 + kg * 8;
        }

        #pragma unroll
        for (int ks = 0; ks < 8; ++ks) {
            short8 b[NCT];
            #pragma unroll
            for (int c = 0; c < NCT; ++c)
                b[c] = *reinterpret_cast<const short8*>(wbase[c] + ks * 32);
            #pragma unroll
            for (int rt = 0; rt < 4; ++rt) {
                const short8 a = *reinterpret_cast<const short8*>(&A[rt * 16 + l15][ks * 32 + kg * 8]);
                #pragma unroll
                for (int c = 0; c < NCT; ++c)
                    acc[rt][c] = __builtin_amdgcn_mfma_f32_16x16x32_bf16(a, b[c], acc[rt][c], 0, 0, 0);
            }
        }

        // epilogue: D col = lane&15 (within tile), row = 4*(lane>>4)+reg
        #pragma unroll
        for (int rt = 0; rt < 4; ++rt) {
            #pragma unroll
            for (int c = 0; c < NCT; ++c) {
                const int col = (wv * NCT + c) * 16 + l15;
                #pragma unroll
                for (int r = 0; r < 4; ++r) {
                    const int row = rt * 16 + kg * 4 + r;
                    const int n   = base + row;
                    if (n < N) {
                        float v = acc[rt][c][r];
                        if (RELU) v = fmaxf(v, 0.f);
                        if (OUTF32)
                            reinterpret_cast<float*>(outp)[(size_t)n * FO + col] = v;
                        else
                            reinterpret_cast<unsigned short*>(outp)[(size_t)n * FO + col] = f2bf(v);
                        if (WRITEQ)
                            outq[(size_t)n * FO + col] = f2fp8(v);
                    }
                }
            }
        }
    }
}

extern "C" void kernel_launch(void* const* d_in, const int* in_sizes, int n_in,
                              void* d_out, int out_size, void* d_ws, size_t ws_size,
                              hipStream_t stream) {
    const int N = 50000;
    const int F = 128;

    const float* x   = (const float*)d_in[0];
    const int*   adj = (const int*)  d_in[1];
    const float* W0  = (const float*)d_in[2];
    const float* W1  = (const float*)d_in[3];
    const float* W2  = (const float*)d_in[4];
    float* logits = (float*)d_out;

    char* ws = (char*)d_ws;
    unsigned short* h1  = (unsigned short*)(ws);                     // 12.8 MB
    unsigned short* h2  = (unsigned short*)(ws + 12800000);          // 12.8 MB
    unsigned char*  xq  = (unsigned char*) (ws + 25600000);          // 6.4 MB
    unsigned char*  h1q = (unsigned char*) (ws + 32000000);          // 6.4 MB
    unsigned char*  h2q = (unsigned char*) (ws + 38400000);          // 6.4 MB
    unsigned short* Wt0 = (unsigned short*)(ws + 44800000);          // 64 KB
    unsigned short* Wt1 = (unsigned short*)(ws + 44800000 + 65536);  // 64 KB
    unsigned short* Wt2 = (unsigned short*)(ws + 44800000 + 131072); // 32 KB

    const int total4 = N * F / 4;   // 1.6M
    prep_kernel<<<(total4 + 255) / 256, 256, 0, stream>>>(x, xq, total4,
                                                          W0, W1, W2, Wt0, Wt1, Wt2);

    const int grid = (N + MT - 1) / MT;   // 782

    sage_layer<128, true,  false, true,  true ><<<grid, 256, 0, stream>>>(x,  xq,  adj, Wt0, h1,     h1q,     N);
    sage_layer<128, true,  false, true,  false><<<grid, 256, 0, stream>>>(h1, h1q, adj, Wt1, h2,     h2q,     N);
    sage_layer< 64, false, true,  false, false><<<grid, 256, 0, stream>>>(h2, h2q, adj, Wt2, logits, nullptr, N);
}